// Round 4
// baseline (12695.103 us; speedup 1.0000x reference)
//
#include <hip/hip_runtime.h>

#define TT 512
#define NB 1024
#define SS 64
#define HH 128
#define NA 10
#define NPAIR 64
#define SLOT_BYTES 4096
#define PROG1_OFF (NPAIR * 2 * SLOT_BYTES)   /* 524288 */
#define PROG2_OFF (PROG1_OFF + 4096)
#define FLAG_BYTES 8192

typedef short bf16x8 __attribute__((ext_vector_type(8)));
typedef float f32x4 __attribute__((ext_vector_type(4)));
typedef unsigned short u16;
typedef unsigned int u32;

__device__ __forceinline__ u16 f2bf(float f){
  union { float f; u32 u; } v; v.f = f;
  return (u16)((v.u + 0x7FFFu + ((v.u >> 16) & 1u)) >> 16);
}
__device__ __forceinline__ float sigm(float v){
  return __builtin_amdgcn_rcpf(1.f + __builtin_amdgcn_exp2f(-1.442695040888963f * v));
}
__device__ __forceinline__ float tanh_(float v){
  return 1.f - 2.f * __builtin_amdgcn_rcpf(1.f + __builtin_amdgcn_exp2f(2.885390081777927f * v));
}
__device__ __forceinline__ void bar_lds(){
  asm volatile("s_waitcnt lgkmcnt(0)" ::: "memory");
  __builtin_amdgcn_s_barrier();
}
__device__ __forceinline__ void wait_ge(u32* f, u32 v){
  while (__hip_atomic_load(f, __ATOMIC_ACQUIRE, __HIP_MEMORY_SCOPE_AGENT) < v)
    __builtin_amdgcn_s_sleep(1);
}

// 128 blocks x 512 threads. Pair p: block p = layer-1 worker, block 64+p = layer-2
// worker, both on batch rows [16p,16p+16). h1(t) handoff via ws slots (2-deep) +
// monotonic progress counters (agent scope).
// Fragment granule layout (as r2/r3, verified): elem (row,j) -> u16 ((j>>3)*16+row)*8+(j&7);
// lane L's A-frag for ktile kt = linear 16B read at u16 idx kt*512 + L*8.
// B-frags for wave w, ktile kt, gate g at u16 idx w*8192 + (kt*4+g)*512 + L*8.
__global__ __launch_bounds__(512, 2)
void lstm_pipe(const float* __restrict__ x,
               const float* __restrict__ Whh1f,
               const float* __restrict__ bih1, const float* __restrict__ bhh1,
               const float* __restrict__ Wih1f,
               const float* __restrict__ Wih2f,
               const float* __restrict__ Whh2f,
               const float* __restrict__ bih2, const float* __restrict__ bhh2,
               const float* __restrict__ Woutf, const float* __restrict__ boutf,
               u16* __restrict__ ws, float* __restrict__ out)
{
  __shared__ __align__(16) u16 lds[71680];   // 140 KB: [wfrag 65536][hd 4096][aux 2048]

  const int tid = threadIdx.x;
  const int w   = tid >> 6;
  const int L   = tid & 63;
  const int Llo = L & 15;
  const int Lhi = L >> 4;
  const int afrag = L*8;
  const int hwIdx = (2*w + (Llo >> 3))*128 + Lhi*32 + (Llo & 7);   // + r*8

  u16* wfrag = lds;            // weight B-fragments (Whh1 or Whh2), 128 KB
  u16* hd    = lds + 65536;    // h dbuf: 2 x 2048 u16
  u16* aux   = lds + 69632;    // L1: xs dbuf (2x1024); L2: W_out frags (2048)

  if (blockIdx.x < NPAIR){
    // ================================ L1 worker ================================
    const int p = blockIdx.x, batch0 = p*16;
    u16* slot  = ws + p*4096;                                   // 2 slots x 4 KB
    u32* prog1 = (u32*)((char*)ws + PROG1_OFF) + p*16;
    u32* prog2 = (u32*)((char*)ws + PROG2_OFF) + p*16;

    // Whh1 -> LDS B-frags
#pragma unroll 4
    for (int it = 0; it < 16; ++it){
      int j = it*512 + tid;
      int l = j & 63, g = (j >> 6) & 3, kt = (j >> 8) & 3, ww = (j >> 10) & 7;
      int col = 128*g + 16*ww + (l & 15);
      int k   = kt*32 + (l >> 4)*8;
      const float* s = Whh1f + col*HH + k;
      bf16x8 v;
#pragma unroll
      for (int e = 0; e < 8; ++e) v[e] = (short)f2bf(s[e]);
      *reinterpret_cast<bf16x8*>(&wfrag[j*8]) = v;
    }
    // Wih1 -> regs (kt 0-1 x g 0-3)
    bf16x8 Wih1r[2][4];
#pragma unroll
    for (int kt = 0; kt < 2; ++kt)
#pragma unroll
      for (int g = 0; g < 4; ++g){
        int col = 128*g + 16*w + Llo;
        const float* s = Wih1f + col*SS + kt*32 + Lhi*8;
        bf16x8 v;
#pragma unroll
        for (int e = 0; e < 8; ++e) v[e] = (short)f2bf(s[e]);
        Wih1r[kt][g] = v;
      }
    float bias1[4];
#pragma unroll
    for (int g = 0; g < 4; ++g){
      int col = 128*g + 16*w + Llo;
      bias1[g] = bih1[col] + bhh1[col];
    }
    // zero both h1 bufs
    *reinterpret_cast<uint4*>(&hd[tid*8]) = make_uint4(0u,0u,0u,0u);

    const int xrow = tid >> 5, xj = (tid & 31)*2;
    const int xsIdx = ((xj >> 3)*16 + xrow)*8 + (xj & 7);
    {
      float2 xv = *reinterpret_cast<const float2*>(x + ((size_t)(batch0 + xrow))*SS + xj);
      *reinterpret_cast<u32*>(&aux[xsIdx]) = (u32)f2bf(xv.x) | ((u32)f2bf(xv.y) << 16);
    }
    float2 xreg = *reinterpret_cast<const float2*>(x + ((size_t)NB + batch0 + xrow)*SS + xj);
    f32x4 c1 = {0.f,0.f,0.f,0.f};
    __syncthreads();

    for (int t = 0; t < TT; ++t){
      if (t >= 2) wait_ge(prog2, (u32)(t-1));        // slot[t&1] free (L2 consumed h1(t-2))

      // stage x(t+1); issue x(t+2)
      *reinterpret_cast<u32*>(&aux[((t+1)&1)*1024 + xsIdx]) =
          (u32)f2bf(xreg.x) | ((u32)f2bf(xreg.y) << 16);
      if (t + 2 < TT)
        xreg = *reinterpret_cast<const float2*>(x + ((size_t)(t+2)*NB + batch0 + xrow)*SS + xj);

      // gates: b1 + h1(t-1)@Whh1(LDS) + x(t)@Wih1(regs)
      const u16* hr = hd + ((t+1)&1)*2048;
      f32x4 acc1[4];
#pragma unroll
      for (int g = 0; g < 4; ++g) acc1[g] = (f32x4){bias1[g],bias1[g],bias1[g],bias1[g]};
#pragma unroll
      for (int kt = 0; kt < 4; ++kt){
        bf16x8 hf = *reinterpret_cast<const bf16x8*>(hr + kt*512 + afrag);
#pragma unroll
        for (int g = 0; g < 4; ++g){
          bf16x8 wf = *reinterpret_cast<const bf16x8*>(&wfrag[w*8192 + (kt*4+g)*512 + afrag]);
          acc1[g] = __builtin_amdgcn_mfma_f32_16x16x32_bf16(hf, wf, acc1[g], 0, 0, 0);
        }
      }
      {
        bf16x8 xf0 = *reinterpret_cast<const bf16x8*>(&aux[(t&1)*1024 + afrag]);
        bf16x8 xf1 = *reinterpret_cast<const bf16x8*>(&aux[(t&1)*1024 + 512 + afrag]);
#pragma unroll
        for (int g = 0; g < 4; ++g){
          acc1[g] = __builtin_amdgcn_mfma_f32_16x16x32_bf16(xf0, Wih1r[0][g], acc1[g], 0, 0, 0);
          acc1[g] = __builtin_amdgcn_mfma_f32_16x16x32_bf16(xf1, Wih1r[1][g], acc1[g], 0, 0, 0);
        }
      }
      // activations -> h1(t) in LDS
      u16* hw_ = hd + (t&1)*2048;
#pragma unroll
      for (int r = 0; r < 4; ++r){
        float iv = sigm(acc1[0][r]);
        float fv = sigm(acc1[1][r]);
        float gv = tanh_(acc1[2][r]);
        float ov = sigm(acc1[3][r]);
        float cn = fv*c1[r] + iv*gv;
        c1[r] = cn;
        hw_[hwIdx + r*8] = f2bf(ov * tanh_(cn));
      }
      bar_lds();                                     // h1(t) LDS complete

      // publish h1(t) -> slot[t&1] (verbatim granule bytes, coalesced 8B/thread)
      {
        uint2 v = *reinterpret_cast<const uint2*>(&hd[(t&1)*2048 + tid*4]);
        *reinterpret_cast<uint2*>((char*)slot + (t&1)*SLOT_BYTES + tid*8) = v;
      }
      __threadfence();                               // agent visibility of publish
      __syncthreads();                               // all threads fenced; end-of-step WAR
      if (tid == 0)
        __hip_atomic_store(prog1, (u32)(t+1), __ATOMIC_RELEASE, __HIP_MEMORY_SCOPE_AGENT);
    }
  } else {
    // ================================ L2 worker ================================
    const int p = blockIdx.x - NPAIR, batch0 = p*16;
    u16* slot  = ws + p*4096;
    u32* prog1 = (u32*)((char*)ws + PROG1_OFF) + p*16;
    u32* prog2 = (u32*)((char*)ws + PROG2_OFF) + p*16;

    // Whh2 -> LDS B-frags
#pragma unroll 4
    for (int it = 0; it < 16; ++it){
      int j = it*512 + tid;
      int l = j & 63, g = (j >> 6) & 3, kt = (j >> 8) & 3, ww = (j >> 10) & 7;
      int col = 128*g + 16*ww + (l & 15);
      int k   = kt*32 + (l >> 4)*8;
      const float* s = Whh2f + col*HH + k;
      bf16x8 v;
#pragma unroll
      for (int e = 0; e < 8; ++e) v[e] = (short)f2bf(s[e]);
      *reinterpret_cast<bf16x8*>(&wfrag[j*8]) = v;
    }
    // Wih2 -> regs (kt 0-3 x g 0-3)
    bf16x8 Wih2r[4][4];
#pragma unroll
    for (int kt = 0; kt < 4; ++kt)
#pragma unroll
      for (int g = 0; g < 4; ++g){
        int col = 128*g + 16*w + Llo;
        const float* s = Wih2f + col*HH + kt*32 + Lhi*8;
        bf16x8 v;
#pragma unroll
        for (int e = 0; e < 8; ++e) v[e] = (short)f2bf(s[e]);
        Wih2r[kt][g] = v;
      }
    float bias2[4];
#pragma unroll
    for (int g = 0; g < 4; ++g){
      int col = 128*g + 16*w + Llo;
      bias2[g] = bih2[col] + bhh2[col];
    }
    const float boutr = (Llo < NA) ? boutf[Llo] : 0.f;
    // W_out frags -> aux
    if (tid < 256){
      int kt = tid >> 6, l = tid & 63, llo = l & 15, lhi = (l >> 4) & 3;
      bf16x8 v;
#pragma unroll
      for (int e = 0; e < 8; ++e) v[e] = 0;
      if (llo < NA){
        const float* s = Woutf + llo*HH + kt*32 + lhi*8;
#pragma unroll
        for (int e = 0; e < 8; ++e) v[e] = (short)f2bf(s[e]);
      }
      *reinterpret_cast<bf16x8*>(&aux[kt*512 + l*8]) = v;
    }
    // zero both h2 bufs
    *reinterpret_cast<uint4*>(&hd[tid*8]) = make_uint4(0u,0u,0u,0u);
    f32x4 c2 = {0.f,0.f,0.f,0.f};
    __syncthreads();

    for (int t = 0; t < TT; ++t){
      wait_ge(prog1, (u32)(t+1));                    // h1(t) published

      // h1(t) A-frags direct from slot (frag-linear layout)
      bf16x8 h1f[4];
#pragma unroll
      for (int kt = 0; kt < 4; ++kt)
        h1f[kt] = *reinterpret_cast<const bf16x8*>((const char*)slot + (t&1)*SLOT_BYTES + kt*1024 + L*16);

      // projection of h2(t-1) on wave 0 (overlaps other waves' gate work)
      if (w == 0 && t >= 1){
        const u16* h2p = hd + ((t+1)&1)*2048;
        f32x4 pacc = {boutr, boutr, boutr, boutr};
#pragma unroll
        for (int kt = 0; kt < 4; ++kt){
          bf16x8 ha = *reinterpret_cast<const bf16x8*>(h2p + kt*512 + afrag);
          bf16x8 wb = *reinterpret_cast<const bf16x8*>(&aux[kt*512 + afrag]);
          pacc = __builtin_amdgcn_mfma_f32_16x16x32_bf16(ha, wb, pacc, 0, 0, 0);
        }
        if (Llo < NA){
          size_t o = ((size_t)(t-1)*NB + batch0 + Lhi*4)*NA + Llo;
#pragma unroll
          for (int r = 0; r < 4; ++r) out[o + (size_t)r*NA] = pacc[r];
        }
      }

      // gates: b2 + h1(t)@Wih2(regs) + h2(t-1)@Whh2(LDS)
      f32x4 acc2[4];
#pragma unroll
      for (int g = 0; g < 4; ++g) acc2[g] = (f32x4){bias2[g],bias2[g],bias2[g],bias2[g]};
#pragma unroll
      for (int kt = 0; kt < 4; ++kt)
#pragma unroll
        for (int g = 0; g < 4; ++g)
          acc2[g] = __builtin_amdgcn_mfma_f32_16x16x32_bf16(h1f[kt], Wih2r[kt][g], acc2[g], 0, 0, 0);
      const u16* h2r = hd + ((t+1)&1)*2048;
#pragma unroll
      for (int kt = 0; kt < 4; ++kt){
        bf16x8 hf = *reinterpret_cast<const bf16x8*>(h2r + kt*512 + afrag);
#pragma unroll
        for (int g = 0; g < 4; ++g){
          bf16x8 wf = *reinterpret_cast<const bf16x8*>(&wfrag[w*8192 + (kt*4+g)*512 + afrag]);
          acc2[g] = __builtin_amdgcn_mfma_f32_16x16x32_bf16(hf, wf, acc2[g], 0, 0, 0);
        }
      }
      // activations -> h2(t)
      u16* hw_ = hd + (t&1)*2048;
#pragma unroll
      for (int r = 0; r < 4; ++r){
        float iv = sigm(acc2[0][r]);
        float fv = sigm(acc2[1][r]);
        float gv = tanh_(acc2[2][r]);
        float ov = sigm(acc2[3][r]);
        float cn = fv*c2[r] + iv*gv;
        c2[r] = cn;
        hw_[hwIdx + r*8] = f2bf(ov * tanh_(cn));
      }
      __syncthreads();                               // h2(t) committed; h1f reads retired
      if (tid == 0)
        __hip_atomic_store(prog2, (u32)(t+1), __ATOMIC_RELEASE, __HIP_MEMORY_SCOPE_AGENT);
    }

    // epilogue: projection of h2(511)
    if (w == 0){
      const u16* h2p = hd + ((TT+1)&1)*2048;
      f32x4 pacc = {boutr, boutr, boutr, boutr};
#pragma unroll
      for (int kt = 0; kt < 4; ++kt){
        bf16x8 ha = *reinterpret_cast<const bf16x8*>(h2p + kt*512 + afrag);
        bf16x8 wb = *reinterpret_cast<const bf16x8*>(&aux[kt*512 + afrag]);
        pacc = __builtin_amdgcn_mfma_f32_16x16x32_bf16(ha, wb, pacc, 0, 0, 0);
      }
      if (Llo < NA){
        size_t o = ((size_t)(TT-1)*NB + batch0 + Lhi*4)*NA + Llo;
#pragma unroll
        for (int r = 0; r < 4; ++r) out[o + (size_t)r*NA] = pacc[r];
      }
    }
  }
}

extern "C" void kernel_launch(void* const* d_in, const int* in_sizes, int n_in,
                              void* d_out, int out_size, void* d_ws, size_t ws_size,
                              hipStream_t stream){
  (void)in_sizes; (void)n_in; (void)out_size; (void)ws_size;
  const float* xp   = (const float*)d_in[0];
  const float* wih1 = (const float*)d_in[1];
  const float* whh1 = (const float*)d_in[2];
  const float* bih1 = (const float*)d_in[3];
  const float* bhh1 = (const float*)d_in[4];
  const float* wih2 = (const float*)d_in[5];
  const float* whh2 = (const float*)d_in[6];
  const float* bih2 = (const float*)d_in[7];
  const float* bhh2 = (const float*)d_in[8];
  const float* wout = (const float*)d_in[9];
  const float* bout = (const float*)d_in[10];
  u16*   wsp  = (u16*)d_ws;
  float* outp = (float*)d_out;

  // flags are re-poisoned 0xAA before every launch -> zero them on-stream
  hipMemsetAsync((char*)d_ws + PROG1_OFF, 0, FLAG_BYTES, stream);
  hipLaunchKernelGGL(lstm_pipe, dim3(2*NPAIR), dim3(512), 0, stream,
                     xp, whh1, bih1, bhh1, wih1, wih2, whh2, bih2, bhh2, wout, bout,
                     wsp, outp);
}

// Round 6
// 1450.503 us; speedup vs baseline: 8.7522x; 8.7522x over previous
//
#include <hip/hip_runtime.h>

#define TT 512
#define NB 1024
#define SS 64
#define HH 128
#define NA 10

typedef short bf16x8 __attribute__((ext_vector_type(8)));
typedef float f32x4 __attribute__((ext_vector_type(4)));
typedef unsigned short u16;
typedef unsigned int u32;

__device__ __forceinline__ u16 f2bf(float f){
  union { float f; u32 u; } v; v.f = f;
  return (u16)((v.u + 0x7FFFu + ((v.u >> 16) & 1u)) >> 16);
}
__device__ __forceinline__ float sigm(float v){
  return __builtin_amdgcn_rcpf(1.f + __builtin_amdgcn_exp2f(-1.442695040888963f * v));
}
__device__ __forceinline__ float tanh_(float v){
  return 1.f - 2.f * __builtin_amdgcn_rcpf(1.f + __builtin_amdgcn_exp2f(2.885390081777927f * v));
}
// LDS-commit-only barrier: global prefetches stay in flight (no vmcnt drain)
__device__ __forceinline__ void bar_lds(){
  asm volatile("s_waitcnt lgkmcnt(0)" ::: "memory");
  __builtin_amdgcn_s_barrier();
}

// 64 blocks x 512 threads (8 waves). Block owns batch rows [16b,16b+16) for all T.
// Wave w owns h-feature slice [16w,16w+16) and its 4 gate tiles (i,f,g,o).
// Fragment granule layout (verified r2-r4): elem (row,j) -> u16 ((j>>3)*16+row)*8+(j&7);
// lane L's A-frag for ktile kt = linear ds_read_b128 at u16 idx kt*512 + L*8.
// B-frags for wave w, ktile kt, gate g at u16 idx w*8192 + (kt*4+g)*512 + L*8.
//
// ALL weights chip-resident: Whh1 in LDS (128 KB B-frags); Wih1/Wih2/Whh2 in
// registers (32+64+64 = 160 VGPR resident; peak live ~250 < the 256 hard cap
// for 512-thread blocks). Zero steady-state global traffic except x and out.
//
// 1 barrier/step pipeline (r3 schedule): region(t) computes
//   part1: acc2(t-1) = b2 + h1(t-1)@Wih2 + h2(t-2)@Whh2 -> h2(t-1)
//          acc1(t)   = b1 + h1(t-1)@Whh1(LDS);   proj(t-2) on wave 0
//   part2: xs(t+1) <- xreg; issue x(t+2); acc1 += x(t)@Wih1; act1 -> h1(t)
__global__ __launch_bounds__(512, 2)
void lstm_fused(const float* __restrict__ x,
                const float* __restrict__ Whh1f,
                const float* __restrict__ bih1, const float* __restrict__ bhh1,
                const float* __restrict__ Wih1f,
                const float* __restrict__ Wih2f,
                const float* __restrict__ Whh2f,
                const float* __restrict__ bih2, const float* __restrict__ bhh2,
                const float* __restrict__ Woutf, const float* __restrict__ boutf,
                float* __restrict__ out)
{
  __shared__ __align__(16) u16 lds[77824];   // 155648 B
  u16* whh1s = lds;            // 65536 u16: Whh1 B-frags
  u16* wos   = lds + 65536;    // 2048: W_out frags
  u16* h1s   = lds + 67584;    // 2 x 2048
  u16* h2s   = lds + 71680;    // 2 x 2048
  u16* xs    = lds + 75776;    // 2 x 1024

  const int tid = threadIdx.x;
  const int w   = tid >> 6;
  const int L   = tid & 63;
  const int Llo = L & 15;
  const int Lhi = L >> 4;
  const int batch0 = blockIdx.x * 16;

  // ---- Whh1 -> LDS B-frags (pattern verified in r4) ----
#pragma unroll 4
  for (int it = 0; it < 16; ++it){
    int j = it*512 + tid;
    int l = j & 63, g = (j >> 6) & 3, kt = (j >> 8) & 3, ww = (j >> 10) & 7;
    int col = 128*g + 16*ww + (l & 15);
    int k   = kt*32 + (l >> 4)*8;
    const float* s = Whh1f + col*HH + k;
    bf16x8 v;
#pragma unroll
    for (int e = 0; e < 8; ++e) v[e] = (short)f2bf(s[e]);
    *reinterpret_cast<bf16x8*>(&whh1s[j*8]) = v;
  }

  // ---- register-resident weights ----
  bf16x8 Wih1r[2][4];                 // 32 VGPR
#pragma unroll
  for (int kt = 0; kt < 2; ++kt)
#pragma unroll
    for (int g = 0; g < 4; ++g){
      int col = 128*g + 16*w + Llo;
      const float* s = Wih1f + col*SS + kt*32 + Lhi*8;
      bf16x8 v;
#pragma unroll
      for (int e = 0; e < 8; ++e) v[e] = (short)f2bf(s[e]);
      Wih1r[kt][g] = v;
    }
  bf16x8 Wih2r[4][4], Whh2r[4][4];    // 64 + 64 VGPR
#pragma unroll
  for (int kt = 0; kt < 4; ++kt)
#pragma unroll
    for (int g = 0; g < 4; ++g){
      int col = 128*g + 16*w + Llo;
      const float* p2 = Wih2f + col*HH + kt*32 + Lhi*8;
      const float* p3 = Whh2f + col*HH + kt*32 + Lhi*8;
      bf16x8 v2, v3;
#pragma unroll
      for (int e = 0; e < 8; ++e){ v2[e] = (short)f2bf(p2[e]); v3[e] = (short)f2bf(p3[e]); }
      Wih2r[kt][g] = v2; Whh2r[kt][g] = v3;
    }

  float bias1[4], bias2[4];
#pragma unroll
  for (int g = 0; g < 4; ++g){
    int col = 128*g + 16*w + Llo;
    bias1[g] = bih1[col] + bhh1[col];
    bias2[g] = bih2[col] + bhh2[col];
  }
  const float boutr = (Llo < NA) ? boutf[Llo] : 0.f;

  // W_out frags -> LDS
  if (tid < 256){
    int kt = tid >> 6, l = tid & 63, llo = l & 15, lhi = (l >> 4) & 3;
    bf16x8 v;
#pragma unroll
    for (int e = 0; e < 8; ++e) v[e] = 0;
    if (llo < NA){
      const float* s = Woutf + llo*HH + kt*32 + lhi*8;
#pragma unroll
      for (int e = 0; e < 8; ++e) v[e] = (short)f2bf(s[e]);
    }
    *reinterpret_cast<bf16x8*>(&wos[kt*512 + l*8]) = v;
  }

  // zero both h1/h2 buffers (h(-1) = h(-2) = 0)
  {
    uint4 z = {0u,0u,0u,0u};
    *reinterpret_cast<uint4*>(h1s + tid*8) = z;
    *reinterpret_cast<uint4*>(h2s + tid*8) = z;
  }

  f32x4 c1 = {0.f,0.f,0.f,0.f}, c2 = {0.f,0.f,0.f,0.f};

  const int afrag = L*8;
  const int hwIdx = (2*w + (Llo >> 3))*128 + Lhi*32 + (Llo & 7);   // + r*8

  const int xrow = tid >> 5;
  const int xj   = (tid & 31)*2;
  const int xsIdx = ((xj >> 3)*16 + xrow)*8 + (xj & 7);

  // prologue: xs[0] <- x(0); xreg <- x(1)
  {
    float2 xv = *reinterpret_cast<const float2*>(x + ((size_t)(batch0 + xrow))*SS + xj);
    *reinterpret_cast<u32*>(&xs[xsIdx]) = (u32)f2bf(xv.x) | ((u32)f2bf(xv.y) << 16);
  }
  float2 xreg = *reinterpret_cast<const float2*>(x + ((size_t)NB + batch0 + xrow)*SS + xj);

  __syncthreads();

  for (int t = 0; t < TT; ++t){
    const u16* h1r = h1s + ((t+1)&1)*2048;   // h1(t-1)
    u16*       h1w = h1s + (t&1)*2048;       // h1(t)
    const u16* h2r = h2s + (t&1)*2048;       // h2(t-2)
    u16*       h2w = h2s + ((t+1)&1)*2048;   // h2(t-1)
    const u16* xsr = xs + (t&1)*1024;        // x(t)
    u16*       xsw = xs + ((t+1)&1)*1024;    // x(t+1)

    // ---- part1: layer2(t-1) gates; layer1 h-side; act2; proj(t-2) ----
    bf16x8 h1f0 = *reinterpret_cast<const bf16x8*>(h1r + afrag);
    bf16x8 h1f1 = *reinterpret_cast<const bf16x8*>(h1r + 512 + afrag);
    bf16x8 h1f2 = *reinterpret_cast<const bf16x8*>(h1r + 1024 + afrag);
    bf16x8 h1f3 = *reinterpret_cast<const bf16x8*>(h1r + 1536 + afrag);

    f32x4 acc2[4];
#pragma unroll
    for (int g = 0; g < 4; ++g){
      f32x4 a = (f32x4){bias2[g], bias2[g], bias2[g], bias2[g]};
      a = __builtin_amdgcn_mfma_f32_16x16x32_bf16(h1f0, Wih2r[0][g], a, 0, 0, 0);
      a = __builtin_amdgcn_mfma_f32_16x16x32_bf16(h1f1, Wih2r[1][g], a, 0, 0, 0);
      a = __builtin_amdgcn_mfma_f32_16x16x32_bf16(h1f2, Wih2r[2][g], a, 0, 0, 0);
      a = __builtin_amdgcn_mfma_f32_16x16x32_bf16(h1f3, Wih2r[3][g], a, 0, 0, 0);
      acc2[g] = a;
    }
    // h2(t-2)@Whh2, h2 frags read per-kt (keeps transients low)
    {
      bf16x8 hf = *reinterpret_cast<const bf16x8*>(h2r + afrag);
#pragma unroll
      for (int g = 0; g < 4; ++g) acc2[g] = __builtin_amdgcn_mfma_f32_16x16x32_bf16(hf, Whh2r[0][g], acc2[g], 0, 0, 0);
      hf = *reinterpret_cast<const bf16x8*>(h2r + 512 + afrag);
#pragma unroll
      for (int g = 0; g < 4; ++g) acc2[g] = __builtin_amdgcn_mfma_f32_16x16x32_bf16(hf, Whh2r[1][g], acc2[g], 0, 0, 0);
      hf = *reinterpret_cast<const bf16x8*>(h2r + 1024 + afrag);
#pragma unroll
      for (int g = 0; g < 4; ++g) acc2[g] = __builtin_amdgcn_mfma_f32_16x16x32_bf16(hf, Whh2r[2][g], acc2[g], 0, 0, 0);
      hf = *reinterpret_cast<const bf16x8*>(h2r + 1536 + afrag);
#pragma unroll
      for (int g = 0; g < 4; ++g) acc2[g] = __builtin_amdgcn_mfma_f32_16x16x32_bf16(hf, Whh2r[3][g], acc2[g], 0, 0, 0);
    }

    if (t > 0){   // layer-2 activations -> h2(t-1)
#pragma unroll
      for (int r = 0; r < 4; ++r){
        float iv = sigm(acc2[0][r]);
        float fv = sigm(acc2[1][r]);
        float gv = tanh_(acc2[2][r]);
        float ov = sigm(acc2[3][r]);
        float cn = fv*c2[r] + iv*gv;
        c2[r] = cn;
        h2w[hwIdx + r*8] = f2bf(ov * tanh_(cn));
      }
    }

    // layer1 h-side: Whh1 frags streamed from LDS per-kt
    f32x4 acc1[4];
#pragma unroll
    for (int g = 0; g < 4; ++g) acc1[g] = (f32x4){bias1[g], bias1[g], bias1[g], bias1[g]};
#pragma unroll
    for (int kt = 0; kt < 4; ++kt){
      bf16x8 wh0 = *reinterpret_cast<const bf16x8*>(&whh1s[w*8192 + (kt*4+0)*512 + afrag]);
      bf16x8 wh1 = *reinterpret_cast<const bf16x8*>(&whh1s[w*8192 + (kt*4+1)*512 + afrag]);
      bf16x8 wh2 = *reinterpret_cast<const bf16x8*>(&whh1s[w*8192 + (kt*4+2)*512 + afrag]);
      bf16x8 wh3 = *reinterpret_cast<const bf16x8*>(&whh1s[w*8192 + (kt*4+3)*512 + afrag]);
      bf16x8 hf = (kt==0) ? h1f0 : (kt==1) ? h1f1 : (kt==2) ? h1f2 : h1f3;
      acc1[0] = __builtin_amdgcn_mfma_f32_16x16x32_bf16(hf, wh0, acc1[0], 0, 0, 0);
      acc1[1] = __builtin_amdgcn_mfma_f32_16x16x32_bf16(hf, wh1, acc1[1], 0, 0, 0);
      acc1[2] = __builtin_amdgcn_mfma_f32_16x16x32_bf16(hf, wh2, acc1[2], 0, 0, 0);
      acc1[3] = __builtin_amdgcn_mfma_f32_16x16x32_bf16(hf, wh3, acc1[3], 0, 0, 0);
    }

    if (w == 0 && t >= 2){   // projection of h2(t-2)
      f32x4 pacc = {boutr, boutr, boutr, boutr};
#pragma unroll
      for (int kt = 0; kt < 4; ++kt){
        bf16x8 ha = *reinterpret_cast<const bf16x8*>(h2r + kt*512 + afrag);
        bf16x8 wb = *reinterpret_cast<const bf16x8*>(&wos[kt*512 + afrag]);
        pacc = __builtin_amdgcn_mfma_f32_16x16x32_bf16(ha, wb, pacc, 0, 0, 0);
      }
      if (Llo < NA){
        size_t o = ((size_t)(t-2)*NB + batch0 + Lhi*4)*NA + Llo;
#pragma unroll
        for (int r = 0; r < 4; ++r) out[o + (size_t)r*NA] = pacc[r];
      }
    }

    // ---- part2: stage x(t+1); prefetch x(t+2); x-side; act1 -> h1(t) ----
    *reinterpret_cast<u32*>(xsw + xsIdx) = (u32)f2bf(xreg.x) | ((u32)f2bf(xreg.y) << 16);
    if (t + 2 < TT)
      xreg = *reinterpret_cast<const float2*>(x + ((size_t)(t+2)*NB + batch0 + xrow)*SS + xj);

    {
      bf16x8 xf0 = *reinterpret_cast<const bf16x8*>(xsr + afrag);
      bf16x8 xf1 = *reinterpret_cast<const bf16x8*>(xsr + 512 + afrag);
#pragma unroll
      for (int g = 0; g < 4; ++g){
        acc1[g] = __builtin_amdgcn_mfma_f32_16x16x32_bf16(xf0, Wih1r[0][g], acc1[g], 0, 0, 0);
        acc1[g] = __builtin_amdgcn_mfma_f32_16x16x32_bf16(xf1, Wih1r[1][g], acc1[g], 0, 0, 0);
      }
    }
#pragma unroll
    for (int r = 0; r < 4; ++r){
      float iv = sigm(acc1[0][r]);
      float fv = sigm(acc1[1][r]);
      float gv = tanh_(acc1[2][r]);
      float ov = sigm(acc1[3][r]);
      float cn = fv*c1[r] + iv*gv;
      c1[r] = cn;
      h1w[hwIdx + r*8] = f2bf(ov * tanh_(cn));
    }

    bar_lds();
  }

  // ---- epilogue: layer2 step for t=511 -> h2(511); proj(510); proj(511) ----
  {
    const u16* h1r = h1s + ((TT+1)&1)*2048;   // h1(511)
    const u16* h2r = h2s + (TT&1)*2048;       // h2(510)
    u16*       h2w = h2s + ((TT+1)&1)*2048;

    bf16x8 h1f0 = *reinterpret_cast<const bf16x8*>(h1r + afrag);
    bf16x8 h1f1 = *reinterpret_cast<const bf16x8*>(h1r + 512 + afrag);
    bf16x8 h1f2 = *reinterpret_cast<const bf16x8*>(h1r + 1024 + afrag);
    bf16x8 h1f3 = *reinterpret_cast<const bf16x8*>(h1r + 1536 + afrag);
    bf16x8 h2f0 = *reinterpret_cast<const bf16x8*>(h2r + afrag);
    bf16x8 h2f1 = *reinterpret_cast<const bf16x8*>(h2r + 512 + afrag);
    bf16x8 h2f2 = *reinterpret_cast<const bf16x8*>(h2r + 1024 + afrag);
    bf16x8 h2f3 = *reinterpret_cast<const bf16x8*>(h2r + 1536 + afrag);

    f32x4 acc2[4];
#pragma unroll
    for (int g = 0; g < 4; ++g){
      f32x4 a = (f32x4){bias2[g], bias2[g], bias2[g], bias2[g]};
      a = __builtin_amdgcn_mfma_f32_16x16x32_bf16(h1f0, Wih2r[0][g], a, 0, 0, 0);
      a = __builtin_amdgcn_mfma_f32_16x16x32_bf16(h1f1, Wih2r[1][g], a, 0, 0, 0);
      a = __builtin_amdgcn_mfma_f32_16x16x32_bf16(h1f2, Wih2r[2][g], a, 0, 0, 0);
      a = __builtin_amdgcn_mfma_f32_16x16x32_bf16(h1f3, Wih2r[3][g], a, 0, 0, 0);
      a = __builtin_amdgcn_mfma_f32_16x16x32_bf16(h2f0, Whh2r[0][g], a, 0, 0, 0);
      a = __builtin_amdgcn_mfma_f32_16x16x32_bf16(h2f1, Whh2r[1][g], a, 0, 0, 0);
      a = __builtin_amdgcn_mfma_f32_16x16x32_bf16(h2f2, Whh2r[2][g], a, 0, 0, 0);
      a = __builtin_amdgcn_mfma_f32_16x16x32_bf16(h2f3, Whh2r[3][g], a, 0, 0, 0);
      acc2[g] = a;
    }
#pragma unroll
    for (int r = 0; r < 4; ++r){
      float iv = sigm(acc2[0][r]);
      float fv = sigm(acc2[1][r]);
      float gv = tanh_(acc2[2][r]);
      float ov = sigm(acc2[3][r]);
      float cn = fv*c2[r] + iv*gv;
      c2[r] = cn;
      h2w[hwIdx + r*8] = f2bf(ov * tanh_(cn));
    }

    if (w == 0){   // proj(510)
      f32x4 pacc = {boutr, boutr, boutr, boutr};
      pacc = __builtin_amdgcn_mfma_f32_16x16x32_bf16(h2f0, *reinterpret_cast<const bf16x8*>(&wos[afrag]),        pacc, 0, 0, 0);
      pacc = __builtin_amdgcn_mfma_f32_16x16x32_bf16(h2f1, *reinterpret_cast<const bf16x8*>(&wos[512 + afrag]),  pacc, 0, 0, 0);
      pacc = __builtin_amdgcn_mfma_f32_16x16x32_bf16(h2f2, *reinterpret_cast<const bf16x8*>(&wos[1024 + afrag]), pacc, 0, 0, 0);
      pacc = __builtin_amdgcn_mfma_f32_16x16x32_bf16(h2f3, *reinterpret_cast<const bf16x8*>(&wos[1536 + afrag]), pacc, 0, 0, 0);
      if (Llo < NA){
        size_t o = ((size_t)(TT-2)*NB + batch0 + Lhi*4)*NA + Llo;
#pragma unroll
        for (int r = 0; r < 4; ++r) out[o + (size_t)r*NA] = pacc[r];
      }
    }

    bar_lds();

    if (w == 0){   // proj(511)
      const u16* h2f = h2s + ((TT+1)&1)*2048;
      bf16x8 a0 = *reinterpret_cast<const bf16x8*>(h2f + afrag);
      bf16x8 a1 = *reinterpret_cast<const bf16x8*>(h2f + 512 + afrag);
      bf16x8 a2 = *reinterpret_cast<const bf16x8*>(h2f + 1024 + afrag);
      bf16x8 a3 = *reinterpret_cast<const bf16x8*>(h2f + 1536 + afrag);
      f32x4 pacc = {boutr, boutr, boutr, boutr};
      pacc = __builtin_amdgcn_mfma_f32_16x16x32_bf16(a0, *reinterpret_cast<const bf16x8*>(&wos[afrag]),        pacc, 0, 0, 0);
      pacc = __builtin_amdgcn_mfma_f32_16x16x32_bf16(a1, *reinterpret_cast<const bf16x8*>(&wos[512 + afrag]),  pacc, 0, 0, 0);
      pacc = __builtin_amdgcn_mfma_f32_16x16x32_bf16(a2, *reinterpret_cast<const bf16x8*>(&wos[1024 + afrag]), pacc, 0, 0, 0);
      pacc = __builtin_amdgcn_mfma_f32_16x16x32_bf16(a3, *reinterpret_cast<const bf16x8*>(&wos[1536 + afrag]), pacc, 0, 0, 0);
      if (Llo < NA){
        size_t o = ((size_t)(TT-1)*NB + batch0 + Lhi*4)*NA + Llo;
#pragma unroll
        for (int r = 0; r < 4; ++r) out[o + (size_t)r*NA] = pacc[r];
      }
    }
  }
}

extern "C" void kernel_launch(void* const* d_in, const int* in_sizes, int n_in,
                              void* d_out, int out_size, void* d_ws, size_t ws_size,
                              hipStream_t stream){
  (void)in_sizes; (void)n_in; (void)out_size; (void)d_ws; (void)ws_size;
  const float* xp   = (const float*)d_in[0];
  const float* wih1 = (const float*)d_in[1];
  const float* whh1 = (const float*)d_in[2];
  const float* bih1 = (const float*)d_in[3];
  const float* bhh1 = (const float*)d_in[4];
  const float* wih2 = (const float*)d_in[5];
  const float* whh2 = (const float*)d_in[6];
  const float* bih2 = (const float*)d_in[7];
  const float* bhh2 = (const float*)d_in[8];
  const float* wout = (const float*)d_in[9];
  const float* bout = (const float*)d_in[10];
  float* outp = (float*)d_out;

  hipLaunchKernelGGL(lstm_fused, dim3(64), dim3(512), 0, stream,
                     xp, whh1, bih1, bhh1, wih1, wih2, whh2, bih2, bhh2, wout, bout,
                     outp);
}